// Round 9
// baseline (2119.603 us; speedup 1.0000x reference)
//
#include <hip/hip_runtime.h>
#include <stdint.h>

typedef _Float16 f16;
typedef _Float16 F16x8 __attribute__((ext_vector_type(8)));
typedef float F32x4 __attribute__((ext_vector_type(4)));

#define MFMA16(a,b,c) __builtin_amdgcn_mfma_f32_16x16x32_f16((a),(b),(c),0,0,0)
#define S12f 2.8853900817779268f    // 2*log2(e): folded into W1,W2,b1,b2
#define SABf (-1.4426950408889634f) // -log2(e): folded into Wa,Wb,ba,bb

// MUST be the builtin (inline-asm v_exp_f32 lacks TRANS-pipe hazard handling; r6/r7 failures)
static __device__ __forceinline__ float exp2_fast(float x){
  return __builtin_amdgcn_exp2f(x);
}
// prescaled pre-acts: a0=2log2e*p1, a1=2log2e*p2, a2+a3=-log2e*(pa+pb)
static __device__ __forceinline__ f16 cfc_act(F32x4 a){
  float e1=exp2_fast(a[0]);
  float e2=exp2_fast(a[1]);
  float es=exp2_fast(a[2]+a[3]);
  float f1=1.f-2.f*__builtin_amdgcn_rcpf(e1+1.f);
  float f2=1.f-2.f*__builtin_amdgcn_rcpf(e2+1.f);
  float s=__builtin_amdgcn_rcpf(1.f+es);
  return (f16)(f1+s*(f2-f1));
}
// frag-interleaved layout: value (k,b) at (k>>3)*128 + b*8 + (k&7)
static __device__ __forceinline__ int fidx(int k,int b){ return ((k>>3)<<7)+(b<<3)+(k&7); }

// ---------------- prep (byte-identical to r8's validated version) ----------------
// H0 (Kpad=128): h0@0..115, dt@124(in-reg), one@125(in-reg). H1 (96): h1@0..75, one@88(in-reg). H2 (64): h2.
// tiles: L0: rt 0..28 x kt 0..3  -> rt*4+kt                 [0,116)
//        L1: rt 0..18 x kt 0..6  -> 116 + rt*7+kt           [116,249)
//        L2: rt 0..15 x kt 0..4  -> 249 + rt*5+kt           [249,329)
//        RO: rt 0..1  x kt 0..1  -> 329 + rt*2+kt           [329,333)
__global__ __launch_bounds__(256) void cfc_prep(
    const float* __restrict__ W10,const float* __restrict__ W20,const float* __restrict__ Wa0,const float* __restrict__ Wb0,
    const float* __restrict__ b10,const float* __restrict__ b20,const float* __restrict__ ba0,const float* __restrict__ bb0,
    const int* __restrict__ M0,
    const float* __restrict__ W11,const float* __restrict__ W21,const float* __restrict__ Wa1,const float* __restrict__ Wb1,
    const float* __restrict__ b11,const float* __restrict__ b21,const float* __restrict__ ba1,const float* __restrict__ bb1,
    const int* __restrict__ M1,
    const float* __restrict__ W12,const float* __restrict__ W22,const float* __restrict__ Wa2,const float* __restrict__ Wb2,
    const float* __restrict__ b12,const float* __restrict__ b22,const float* __restrict__ ba2,const float* __restrict__ bb2,
    const int* __restrict__ M2,
    const float* __restrict__ Wo, f16* __restrict__ ws)
{
  int idx=blockIdx.x*256+threadIdx.x;
  if(idx>=21312) return;
  int tile=idx>>6, lane=idx&63, ml=lane&15, grp=lane>>4;
  F16x8 fr;
  if(tile<329){
    int rt,kt,c,lay;
    const float *w1,*w2,*wa,*wb,*c1,*c2,*ca,*cb; const int* M;
    if(tile<116){ rt=tile>>2; kt=tile&3; c=117; lay=0;
      w1=W10;w2=W20;wa=Wa0;wb=Wb0;M=M0;c1=b10;c2=b20;ca=ba0;cb=bb0; }
    else if(tile<249){ int u=tile-116; rt=u/7; kt=u-rt*7; c=192; lay=1;
      w1=W11;w2=W21;wa=Wa1;wb=Wb1;M=M1;c1=b11;c2=b21;ca=ba1;cb=bb1; }
    else { int u=tile-249; rt=u/5; kt=u-rt*5; c=140; lay=2;
      w1=W12;w2=W22;wa=Wa2;wb=Wb2;M=M2;c1=b12;c2=b22;ca=ba2;cb=bb2; }
    int n=rt*4+(ml>>2), mat=ml&3;
    const float* W =(mat==0)?w1:(mat==1)?w2:(mat==2)?wa:wb;
    const float* Bv=(mat==0)?c1:(mat==1)?c2:(mat==2)?ca:cb;
    float sc=(mat<2)?S12f:SABf;
    int k0=kt*32+grp*8;
    #pragma unroll
    for(int j=0;j<8;++j){
      int k=k0+j; float v=0.f; int col=-1;
      if(lay==0){       // x=[dt@ref0, h0@ref1..116]; k<116->h0, k==124->dt, k==125->bias
        if(k<116) col=1+k; else if(k==124) col=0; else if(k==125) col=-2;
      } else if(lay==1){ // x=[h0(116), h1(76)]; k<116->h0, 128<=k<204->h1, k==125->bias
        if(k<116) col=k; else if(k>=128 && k<204) col=116+(k-128); else if(k==125) col=-2;
      } else {           // x=[h1(76), h2(64)]; k<76->h1, 96<=k<160->h2, k==88->bias
        if(k<76) col=k; else if(k>=96 && k<160) col=76+(k-96); else if(k==88) col=-2;
      }
      if(col>=0){ v=W[n*c+col]; if(mat<2) v*=(float)M[n*c+col]; }
      else if(col==-2){ v=Bv[n]; }
      fr[j]=(f16)(v*sc);
    }
  } else {
    int u=tile-329, rt=u>>1, kt=u&1;
    int o=rt*16+ml, k0=kt*32+grp*8;
    #pragma unroll
    for(int j=0;j<8;++j) fr[j]=(f16)Wo[o*64+k0+j];
  }
  ((F16x8*)ws)[idx]=fr;
}

// ---------------- main: 2 phases/step via cross-step layer pipelining ----------------
// iteration I: phase Y = { L1(I): h1^{I+1}=cell1(h0^{I+1},h1^I); RO(y_{I-1}) }
//              phase X = { L2(I): h2^{I+1}=cell2(h1^{I+1},h2^I); L0(I+1): h0^{I+2}=cell0(dt_{I+1},h0^{I+1}) }
// parity: Y reads H0[P],H1[P^1],H2[P^1]; writes H1[P].  X reads H0[P],H1[P],H2[P^1]; writes H2[P],H0[P^1].
__global__ __launch_bounds__(512,1) void cfc_main(
    const float* __restrict__ dtp, const float* __restrict__ hxp,
    const float* __restrict__ boutp, const f16* __restrict__ ws, float* __restrict__ outp)
{
  const int tid=threadIdx.x, lane=tid&63, w=tid>>6;
  const int b_l=lane&15, g_l=lane>>4;
  const int gb0=blockIdx.x*16;
  const f16 onef=(f16)1.f;

  __shared__ alignas(16) f16 H0[2][2048];   // h0, Kpad=128 (cols 116-127 stay 0)
  __shared__ alignas(16) f16 H1[2][1536];   // h1, Kpad=96  (cols 76-95 stay 0)
  __shared__ alignas(16) f16 H2[2][1024];   // h2, K=64
  __shared__ f16 DTS[16448];                // [t][b] stride 16, rows 1024-1025 zero

  const F16x8* wsf=(const F16x8*)ws;
  const int cnt0=(w<5)?4:3, cnt1=(w<3)?3:2;
  const bool isro=(w==5)||(w==6);

  // resident weight fragments (identical ownership to r8)
  F16x8 wl0[4][4], wl1[3][7], wl2[2][5], wro[2];
  #pragma unroll
  for(int i=0;i<4;++i) if(i<cnt0){ int rt=w+8*i;
    #pragma unroll
    for(int kt=0;kt<4;++kt) wl0[i][kt]=wsf[(rt*4+kt)*64+lane]; }
  #pragma unroll
  for(int i=0;i<3;++i) if(i<cnt1){ int rt=w+8*i;
    #pragma unroll
    for(int kt=0;kt<7;++kt) wl1[i][kt]=wsf[(116+rt*7+kt)*64+lane]; }
  #pragma unroll
  for(int i=0;i<2;++i){ int rt=w+8*i;
    #pragma unroll
    for(int kt=0;kt<5;++kt) wl2[i][kt]=wsf[(249+rt*5+kt)*64+lane]; }
  if(isro){ int rt=w-5;
    wro[0]=wsf[(329+rt*2+0)*64+lane];
    wro[1]=wsf[(329+rt*2+1)*64+lane]; }

  F32x4 bias_ro; float* op=0;
  if(isro){ int o0=(w-5)*16+g_l*4;
    bias_ro[0]=boutp[o0]; bias_ro[1]=boutp[o0+1]; bias_ro[2]=boutp[o0+2]; bias_ro[3]=boutp[o0+3];
    op=outp + (size_t)(gb0+b_l)*1024*32 + o0;
  }

  const int wbase=fidx(4*w+g_l,b_l);   // n = 4w+g_l+32*i  ->  wbase + 512*i

  // ---- init ----
  for(int i=tid;i<4096;i+=512) ((f16*)H0)[i]=(f16)0.f;
  for(int i=tid;i<3072;i+=512) ((f16*)H1)[i]=(f16)0.f;
  for(int i=tid;i<2048;i+=512) ((f16*)H2)[i]=(f16)0.f;
  for(int i=tid;i<16384;i+=512){ int b=i>>10, t=i&1023; DTS[t*16+b]=(f16)dtp[(size_t)(gb0+b)*1024+t]; }
  if(tid<64) DTS[16384+tid]=(f16)0.f;
  __syncthreads();
  for(int i=tid;i<4096;i+=512){ int b=i>>8,u=i&255; f16 v=(f16)hxp[(size_t)(gb0+b)*256+u];
    if(u<116) H0[1][fidx(u,b)]=v;
    else if(u<192) H1[1][fidx(u-116,b)]=v;
    else H2[1][fidx(u-192,b)]=v;
  }
  __syncthreads();

  // ---- prologue: h0^1 = L0(dt_0, h0^0) -> H0[0] ----
  {
    F16x8 Af0=((const F16x8*)H0[1])[0*64+lane];
    F16x8 Af1=((const F16x8*)H0[1])[1*64+lane];
    F16x8 Af2=((const F16x8*)H0[1])[2*64+lane];
    F16x8 Af3=((const F16x8*)H0[1])[3*64+lane];
    f16 dtv=DTS[b_l];
    if(g_l==3){ Af3[4]=dtv; Af3[5]=onef; }
    F32x4 acc[4];
    #pragma unroll
    for(int i=0;i<4;++i) if(i<cnt0){ acc[i][0]=0.f;acc[i][1]=0.f;acc[i][2]=0.f;acc[i][3]=0.f; }
    #pragma unroll
    for(int i=0;i<4;++i) if(i<cnt0){
      acc[i]=MFMA16(wl0[i][0],Af0,acc[i]); acc[i]=MFMA16(wl0[i][1],Af1,acc[i]);
      acc[i]=MFMA16(wl0[i][2],Af2,acc[i]); acc[i]=MFMA16(wl0[i][3],Af3,acc[i]);
    }
    #pragma unroll
    for(int i=0;i<4;++i) if(i<cnt0) H0[0][wbase+512*i]=cfc_act(acc[i]);
  }
  __syncthreads();

  for(int t2=0;t2<1024;t2+=2){
    #pragma unroll
    for(int u=0;u<2;++u){
      const int P=u; const int I=t2+u;
      const bool doro = isro && (I>0);
      // ---------- Phase Y: L1(I) + RO(y_{I-1}) ----------
      {
        F16x8 Bf0=((const F16x8*)H0[P])[0*64+lane];
        F16x8 Bf1=((const F16x8*)H0[P])[1*64+lane];
        F16x8 Bf2=((const F16x8*)H0[P])[2*64+lane];
        F16x8 Bf3=((const F16x8*)H0[P])[3*64+lane];
        F16x8 Bf4=((const F16x8*)H1[P^1])[0*64+lane];
        F16x8 Bf5=((const F16x8*)H1[P^1])[1*64+lane];
        F16x8 Bf6=((const F16x8*)H1[P^1])[2*64+lane];
        if(g_l==3) Bf3[5]=onef;                       // bias-one col k=125
        F16x8 r0,r1;
        if(doro){ r0=((const F16x8*)H2[P^1])[lane]; r1=((const F16x8*)H2[P^1])[64+lane]; }
        F32x4 acc[3];
        #pragma unroll
        for(int i=0;i<3;++i) if(i<cnt1){ acc[i][0]=0.f;acc[i][1]=0.f;acc[i][2]=0.f;acc[i][3]=0.f; }
        #pragma unroll
        for(int i=0;i<3;++i) if(i<cnt1){
          acc[i]=MFMA16(wl1[i][0],Bf0,acc[i]); acc[i]=MFMA16(wl1[i][1],Bf1,acc[i]);
          acc[i]=MFMA16(wl1[i][2],Bf2,acc[i]); acc[i]=MFMA16(wl1[i][3],Bf3,acc[i]);
          acc[i]=MFMA16(wl1[i][4],Bf4,acc[i]); acc[i]=MFMA16(wl1[i][5],Bf5,acc[i]);
          acc[i]=MFMA16(wl1[i][6],Bf6,acc[i]);
        }
        if(doro){
          F32x4 r=bias_ro;
          r=MFMA16(wro[0],r0,r); r=MFMA16(wro[1],r1,r);
          *(F32x4*)op=r; op+=32;
        }
        #pragma unroll
        for(int i=0;i<3;++i) if(i<cnt1) H1[P][wbase+512*i]=cfc_act(acc[i]);
      }
      __syncthreads();
      // ---------- Phase X: L2(I) + L0(I+1) ----------
      {
        F16x8 Af0=((const F16x8*)H0[P])[0*64+lane];
        F16x8 Af1=((const F16x8*)H0[P])[1*64+lane];
        F16x8 Af2=((const F16x8*)H0[P])[2*64+lane];
        F16x8 Af3=((const F16x8*)H0[P])[3*64+lane];
        F16x8 Cf0=((const F16x8*)H1[P])[0*64+lane];
        F16x8 Cf1=((const F16x8*)H1[P])[1*64+lane];
        F16x8 Cf2=((const F16x8*)H1[P])[2*64+lane];
        F16x8 Cf3=((const F16x8*)H2[P^1])[0*64+lane];
        F16x8 Cf4=((const F16x8*)H2[P^1])[1*64+lane];
        f16 dtv=DTS[(I+1)*16+b_l];
        if(g_l==3){ Af3[4]=dtv; Af3[5]=onef; Cf2[0]=onef; }  // dt@124, one@125 (L0); one@88 (L2)
        F32x4 acc0[4], acc2[2];
        #pragma unroll
        for(int i=0;i<4;++i) if(i<cnt0){ acc0[i][0]=0.f;acc0[i][1]=0.f;acc0[i][2]=0.f;acc0[i][3]=0.f; }
        #pragma unroll
        for(int i=0;i<2;++i){ acc2[i][0]=0.f;acc2[i][1]=0.f;acc2[i][2]=0.f;acc2[i][3]=0.f; }
        #pragma unroll
        for(int i=0;i<4;++i) if(i<cnt0){
          acc0[i]=MFMA16(wl0[i][0],Af0,acc0[i]); acc0[i]=MFMA16(wl0[i][1],Af1,acc0[i]);
          acc0[i]=MFMA16(wl0[i][2],Af2,acc0[i]); acc0[i]=MFMA16(wl0[i][3],Af3,acc0[i]);
        }
        #pragma unroll
        for(int i=0;i<2;++i){
          acc2[i]=MFMA16(wl2[i][0],Cf0,acc2[i]); acc2[i]=MFMA16(wl2[i][1],Cf1,acc2[i]);
          acc2[i]=MFMA16(wl2[i][2],Cf2,acc2[i]); acc2[i]=MFMA16(wl2[i][3],Cf3,acc2[i]);
          acc2[i]=MFMA16(wl2[i][4],Cf4,acc2[i]);
        }
        #pragma unroll
        for(int i=0;i<4;++i) if(i<cnt0) H0[P^1][wbase+512*i]=cfc_act(acc0[i]);
        #pragma unroll
        for(int i=0;i<2;++i) H2[P][wbase+512*i]=cfc_act(acc2[i]);
      }
      __syncthreads();
    }
  }
  // ---------- tail readout y_1023: h2^{1024} is in H2[1] (X_1023, P=1) ----------
  if(isro){
    F16x8 r0=((const F16x8*)H2[1])[lane];
    F16x8 r1=((const F16x8*)H2[1])[64+lane];
    F32x4 r=bias_ro;
    r=MFMA16(wro[0],r0,r); r=MFMA16(wro[1],r1,r);
    *(F32x4*)op=r;
  }
}

extern "C" void kernel_launch(void* const* d_in, const int* in_sizes, int n_in,
                              void* d_out, int out_size, void* d_ws, size_t ws_size,
                              hipStream_t stream)
{
  (void)in_sizes; (void)n_in; (void)out_size; (void)ws_size;
  f16* ws=(f16*)d_ws;
  cfc_prep<<<84,256,0,stream>>>(
    (const float*)d_in[2],(const float*)d_in[3],(const float*)d_in[4],(const float*)d_in[5],
    (const float*)d_in[6],(const float*)d_in[7],(const float*)d_in[8],(const float*)d_in[9],
    (const int*)d_in[10],
    (const float*)d_in[11],(const float*)d_in[12],(const float*)d_in[13],(const float*)d_in[14],
    (const float*)d_in[15],(const float*)d_in[16],(const float*)d_in[17],(const float*)d_in[18],
    (const int*)d_in[19],
    (const float*)d_in[20],(const float*)d_in[21],(const float*)d_in[22],(const float*)d_in[23],
    (const float*)d_in[24],(const float*)d_in[25],(const float*)d_in[26],(const float*)d_in[27],
    (const int*)d_in[28],
    (const float*)d_in[29], ws);
  cfc_main<<<32,512,0,stream>>>(
    (const float*)d_in[0],(const float*)d_in[1],
    (const float*)d_in[30], ws, (float*)d_out);
}

// Round 10
// 1464.908 us; speedup vs baseline: 1.4469x; 1.4469x over previous
//
#include <hip/hip_runtime.h>
#include <stdint.h>

typedef _Float16 f16;
typedef _Float16 F16x8 __attribute__((ext_vector_type(8)));
typedef float F32x4 __attribute__((ext_vector_type(4)));

#define MFMA16(a,b,c) __builtin_amdgcn_mfma_f32_16x16x32_f16((a),(b),(c),0,0,0)
#define S12f 2.8853900817779268f    // 2*log2(e): folded into W1,W2,b1,b2
#define SABf (-1.4426950408889634f) // -log2(e): folded into Wa,Wb,ba,bb

// MUST be the builtin: raw inline-asm v_exp_f32 lacks the TRANS-pipe hazard
// wait-states before dependent VALU reads (r6/r7 correctness failures).
static __device__ __forceinline__ float exp2_fast(float x){
  return __builtin_amdgcn_exp2f(x);
}
// prescaled pre-acts: a0=2log2e*p1, a1=2log2e*p2, a2+a3=-log2e*(pa+pb)
// tanh(p)=1-2*rcp(exp2(2log2e*p)+1); sigm(z)=rcp(1+exp2(-log2e*z)); inf-safe
static __device__ __forceinline__ f16 cfc_act(F32x4 a){
  float e1=exp2_fast(a[0]);
  float e2=exp2_fast(a[1]);
  float es=exp2_fast(a[2]+a[3]);
  float f1=1.f-2.f*__builtin_amdgcn_rcpf(e1+1.f);
  float f2=1.f-2.f*__builtin_amdgcn_rcpf(e2+1.f);
  float s=__builtin_amdgcn_rcpf(1.f+es);
  return (f16)(f1+s*(f2-f1));
}
// frag-interleaved x layout: value (k,b) lives at (k>>3)*128 + b*8 + (k&7)
static __device__ __forceinline__ int fidx(int k,int b){ return ((k>>3)<<7)+(b<<3)+(k&7); }

// ---------------- prep: A-fragments (rows interleaved (n,mat)), bias in const-1 column, exp2-prescaled ----------------
// tiles: L0: rt 0..28 x kt 0..3 (c=117, bias col 117, Kpad=128)  -> tile = rt*4+kt        [0,116)
//        L1: rt 0..18 x kt 0..5 (c=192 exact)                    -> 116 + rt*6+kt         [116,230)
//        L2: rt 0..15 x kt 0..4 (c=140, bias col 140, Kpad=160)  -> 230 + rt*5+kt         [230,310)
//        RO: rt 0..1  x kt 0..1 (plain rows, c=64, unscaled)     -> 310 + rt*2+kt         [310,314)
__global__ __launch_bounds__(256) void cfc_prep(
    const float* __restrict__ W10,const float* __restrict__ W20,const float* __restrict__ Wa0,const float* __restrict__ Wb0,
    const float* __restrict__ b10,const float* __restrict__ b20,const float* __restrict__ ba0,const float* __restrict__ bb0,
    const int* __restrict__ M0,
    const float* __restrict__ W11,const float* __restrict__ W21,const float* __restrict__ Wa1,const float* __restrict__ Wb1,
    const int* __restrict__ M1,
    const float* __restrict__ W12,const float* __restrict__ W22,const float* __restrict__ Wa2,const float* __restrict__ Wb2,
    const float* __restrict__ b12,const float* __restrict__ b22,const float* __restrict__ ba2,const float* __restrict__ bb2,
    const int* __restrict__ M2,
    const float* __restrict__ Wo, f16* __restrict__ ws)
{
  int idx=blockIdx.x*256+threadIdx.x;
  if(idx>=20096) return;
  int tile=idx>>6, lane=idx&63, ml=lane&15, grp=lane>>4;
  F16x8 fr;
  if(tile<310){
    int rt,kt,c;
    const float *w1,*w2,*wa,*wb,*c1,*c2,*ca,*cb; const int* M;
    if(tile<116){ rt=tile>>2; kt=tile&3; c=117; w1=W10;w2=W20;wa=Wa0;wb=Wb0;M=M0;c1=b10;c2=b20;ca=ba0;cb=bb0; }
    else if(tile<230){ int u=tile-116; rt=u/6; kt=u-rt*6; c=192; w1=W11;w2=W21;wa=Wa1;wb=Wb1;M=M1;c1=0;c2=0;ca=0;cb=0; }
    else { int u=tile-230; rt=u/5; kt=u-rt*5; c=140; w1=W12;w2=W22;wa=Wa2;wb=Wb2;M=M2;c1=b12;c2=b22;ca=ba2;cb=bb2; }
    int n=rt*4+(ml>>2), mat=ml&3;
    const float* W =(mat==0)?w1:(mat==1)?w2:(mat==2)?wa:wb;
    const float* Bv=(mat==0)?c1:(mat==1)?c2:(mat==2)?ca:cb;
    float sc=(mat<2)?S12f:SABf;
    int k0=kt*32+grp*8;
    #pragma unroll
    for(int j=0;j<8;++j){
      int k=k0+j; float v=0.f;
      if(k<c){ v=W[n*c+k]; if(mat<2) v*=(float)M[n*c+k]; }
      else if(k==c && Bv){ v=Bv[n]; }        // bias column (multiplied by const-1 input)
      fr[j]=(f16)(v*sc);
    }
  } else {
    int u=tile-310, rt=u>>1, kt=u&1;
    int o=rt*16+ml, k0=kt*32+grp*8;
    #pragma unroll
    for(int j=0;j<8;++j) fr[j]=(f16)Wo[o*64+k0+j];
  }
  ((F16x8*)ws)[idx]=fr;
}

// ---------------- main: 32 WGs x 512 thr x 16 batch rows; weights resident; parity double-buffer, 3 barriers/step ----------------
__global__ __launch_bounds__(512,1) void cfc_main(
    const float* __restrict__ dtp, const float* __restrict__ hxp,
    const float* __restrict__ b11,const float* __restrict__ b21,const float* __restrict__ ba1,const float* __restrict__ bb1,
    const float* __restrict__ boutp, const f16* __restrict__ ws, float* __restrict__ outp)
{
  const int tid=threadIdx.x, lane=tid&63, w=tid>>6;
  const int b_l=lane&15, g_l=lane>>4;
  const int gb0=blockIdx.x*16;

  __shared__ alignas(16) f16 X0[2][2048];   // [dt | h0 | 1 | pad]  Kpad=128
  __shared__ alignas(16) f16 X1[2][3072];   // [h0 | h1]            K=192
  __shared__ alignas(16) f16 X2[2][2560];   // [h1 | h2 | 1 | pad]  Kpad=160
  __shared__ alignas(16) f16 XR[2][1024];   // h2 frag for readout, K=64
  __shared__ f16 DTS[1024*16];              // [t][b]

  const F16x8* wsf=(const F16x8*)ws;
  const int cnt0=(w<5)?4:3, cnt1=(w<3)?3:2;
  const bool isro=(w==5)||(w==6);

  // resident weight fragments (waves 5-6 reuse wl0[3] slots for readout W)
  F16x8 wl0[4][4], wl1[3][6], wl2[2][5];
  #pragma unroll
  for(int i=0;i<4;++i) if(i<cnt0){ int rt=w+8*i;
    #pragma unroll
    for(int kt=0;kt<4;++kt) wl0[i][kt]=wsf[(rt*4+kt)*64+lane]; }
  #pragma unroll
  for(int i=0;i<3;++i) if(i<cnt1){ int rt=w+8*i;
    #pragma unroll
    for(int kt=0;kt<6;++kt) wl1[i][kt]=wsf[(116+rt*6+kt)*64+lane]; }
  #pragma unroll
  for(int i=0;i<2;++i){ int rt=w+8*i;
    #pragma unroll
    for(int kt=0;kt<5;++kt) wl2[i][kt]=wsf[(230+rt*5+kt)*64+lane]; }
  if(isro){ int rt=w-5;
    wl0[3][0]=wsf[(310+rt*2+0)*64+lane];
    wl0[3][1]=wsf[(310+rt*2+1)*64+lane]; }

  F32x4 bias1r[3];
  #pragma unroll
  for(int i=0;i<3;++i) if(i<cnt1){ int n=(w+8*i)*4+g_l;
    bias1r[i][0]=b11[n]*S12f; bias1r[i][1]=b21[n]*S12f; bias1r[i][2]=ba1[n]*SABf; bias1r[i][3]=bb1[n]*SABf; }

  float* op=0;
  if(isro){ int o0=(w-5)*16+g_l*4;
    bias1r[2][0]=boutp[o0]; bias1r[2][1]=boutp[o0+1]; bias1r[2][2]=boutp[o0+2]; bias1r[2][3]=boutp[o0+3];
    op=outp + (size_t)(gb0+b_l)*1024*32 + o0;
  }

  // per-thread LDS write bases (tile i adds 512*i)
  const int wlo=fidx(4*w+g_l,b_l);        // X1 h0-part / X2 h1-part / XR
  const int w0a=fidx(1+4*w+g_l,b_l);      // X0 h0-part
  const int w1b=fidx(116+4*w+g_l,b_l);    // X1 h1-part
  const int w2c=fidx(76+4*w+g_l,b_l);     // X2 h2-part

  // ---- init LDS ----
  for(int i=tid;i<4096;i+=512){ ((f16*)X0)[i]=(f16)0.f; }
  for(int i=tid;i<6144;i+=512){ ((f16*)X1)[i]=(f16)0.f; }
  for(int i=tid;i<5120;i+=512){ ((f16*)X2)[i]=(f16)0.f; }
  for(int i=tid;i<16384;i+=512){ int b=i>>10, t=i&1023; DTS[t*16+b]=(f16)dtp[(size_t)(gb0+b)*1024+t]; }
  __syncthreads();
  for(int i=tid;i<4096;i+=512){ int b=i>>8,u=i&255; f16 v=(f16)hxp[(size_t)(gb0+b)*256+u];
    if(u<116){ X0[0][fidx(1+u,b)]=v; X1[0][fidx(u,b)]=v; }
    else if(u<192){ int n=u-116; X1[0][fidx(116+n,b)]=v; X2[0][fidx(n,b)]=v; }
    else { int n=u-192; X2[0][fidx(76+n,b)]=v; }
  }
  if(tid<16){
    X0[0][fidx(0,tid)]=DTS[tid];
    X0[0][fidx(117,tid)]=(f16)1.f; X0[1][fidx(117,tid)]=(f16)1.f;
    X2[0][fidx(140,tid)]=(f16)1.f; X2[1][fidx(140,tid)]=(f16)1.f;
  }
  __syncthreads();

  for(int t2=0;t2<1024;t2+=2){
    #pragma unroll
    for(int u=0;u<2;++u){
      const int P=u; const int T=t2+u;
      // ---------- Phase A: L0 (+ readout of T-1 on waves 5,6) ----------
      {
        F16x8 Bf0=((const F16x8*)X0[P])[0*64+lane];
        F16x8 Bf1=((const F16x8*)X0[P])[1*64+lane];
        F16x8 Bf2=((const F16x8*)X0[P])[2*64+lane];
        F16x8 Bf3=((const F16x8*)X0[P])[3*64+lane];
        F32x4 acc[4];
        #pragma unroll
        for(int i=0;i<4;++i) if(i<cnt0){ acc[i][0]=0.f;acc[i][1]=0.f;acc[i][2]=0.f;acc[i][3]=0.f; }
        #pragma unroll
        for(int i=0;i<4;++i) if(i<cnt0){
          acc[i]=MFMA16(wl0[i][0],Bf0,acc[i]); acc[i]=MFMA16(wl0[i][1],Bf1,acc[i]);
          acc[i]=MFMA16(wl0[i][2],Bf2,acc[i]); acc[i]=MFMA16(wl0[i][3],Bf3,acc[i]);
        }
        if(isro && T>0){
          F16x8 br0=((const F16x8*)XR[P])[lane];
          F16x8 br1=((const F16x8*)XR[P])[64+lane];
          F32x4 r=bias1r[2];
          r=MFMA16(wl0[3][0],br0,r); r=MFMA16(wl0[3][1],br1,r);
          *(F32x4*)op=r; op+=32;
        }
        #pragma unroll
        for(int i=0;i<4;++i) if(i<cnt0){
          f16 hv=cfc_act(acc[i]);
          X0[P^1][w0a+512*i]=hv; X1[P][wlo+512*i]=hv;
        }
      }
      __syncthreads();
      // ---------- Phase B: L1 ----------
      {
        F16x8 Bf0=((const F16x8*)X1[P])[0*64+lane];
        F16x8 Bf1=((const F16x8*)X1[P])[1*64+lane];
        F16x8 Bf2=((const F16x8*)X1[P])[2*64+lane];
        F16x8 Bf3=((const F16x8*)X1[P])[3*64+lane];
        F16x8 Bf4=((const F16x8*)X1[P])[4*64+lane];
        F16x8 Bf5=((const F16x8*)X1[P])[5*64+lane];
        F32x4 acc[3];
        #pragma unroll
        for(int i=0;i<3;++i) if(i<cnt1) acc[i]=bias1r[i];
        #pragma unroll
        for(int i=0;i<3;++i) if(i<cnt1){
          acc[i]=MFMA16(wl1[i][0],Bf0,acc[i]); acc[i]=MFMA16(wl1[i][1],Bf1,acc[i]);
          acc[i]=MFMA16(wl1[i][2],Bf2,acc[i]); acc[i]=MFMA16(wl1[i][3],Bf3,acc[i]);
          acc[i]=MFMA16(wl1[i][4],Bf4,acc[i]); acc[i]=MFMA16(wl1[i][5],Bf5,acc[i]);
        }
        #pragma unroll
        for(int i=0;i<3;++i) if(i<cnt1){
          f16 hv=cfc_act(acc[i]);
          X1[P^1][w1b+512*i]=hv; X2[P][wlo+512*i]=hv;
        }
      }
      __syncthreads();
      // ---------- Phase C: L2 (+ dt prefetch on wave 7) ----------
      {
        F16x8 Cf0=((const F16x8*)X2[P])[0*64+lane];
        F16x8 Cf1=((const F16x8*)X2[P])[1*64+lane];
        F16x8 Cf2=((const F16x8*)X2[P])[2*64+lane];
        F16x8 Cf3=((const F16x8*)X2[P])[3*64+lane];
        F16x8 Cf4=((const F16x8*)X2[P])[4*64+lane];
        F32x4 acc[2];
        #pragma unroll
        for(int i=0;i<2;++i){ acc[i][0]=0.f;acc[i][1]=0.f;acc[i][2]=0.f;acc[i][3]=0.f; }
        #pragma unroll
        for(int i=0;i<2;++i){
          acc[i]=MFMA16(wl2[i][0],Cf0,acc[i]); acc[i]=MFMA16(wl2[i][1],Cf1,acc[i]);
          acc[i]=MFMA16(wl2[i][2],Cf2,acc[i]); acc[i]=MFMA16(wl2[i][3],Cf3,acc[i]);
          acc[i]=MFMA16(wl2[i][4],Cf4,acc[i]);
        }
        #pragma unroll
        for(int i=0;i<2;++i){
          f16 hv=cfc_act(acc[i]);
          X2[P^1][w2c+512*i]=hv; XR[P^1][wlo+512*i]=hv;
        }
        if(w==7 && lane<16 && T<1023) X0[P^1][fidx(0,lane)]=DTS[(T+1)*16+lane];
      }
      __syncthreads();
    }
  }
  // ---------- tail readout y_1023 (h2 of t=1023 is in XR[0]) ----------
  if(isro){
    F16x8 br0=((const F16x8*)XR[0])[lane];
    F16x8 br1=((const F16x8*)XR[0])[64+lane];
    F32x4 r=bias1r[2];
    r=MFMA16(wl0[3][0],br0,r); r=MFMA16(wl0[3][1],br1,r);
    *(F32x4*)op=r;
  }
}

extern "C" void kernel_launch(void* const* d_in, const int* in_sizes, int n_in,
                              void* d_out, int out_size, void* d_ws, size_t ws_size,
                              hipStream_t stream)
{
  (void)in_sizes; (void)n_in; (void)out_size; (void)ws_size;
  f16* ws=(f16*)d_ws;
  cfc_prep<<<79,256,0,stream>>>(
    (const float*)d_in[2],(const float*)d_in[3],(const float*)d_in[4],(const float*)d_in[5],
    (const float*)d_in[6],(const float*)d_in[7],(const float*)d_in[8],(const float*)d_in[9],
    (const int*)d_in[10],
    (const float*)d_in[11],(const float*)d_in[12],(const float*)d_in[13],(const float*)d_in[14],
    (const int*)d_in[19],
    (const float*)d_in[20],(const float*)d_in[21],(const float*)d_in[22],(const float*)d_in[23],
    (const float*)d_in[24],(const float*)d_in[25],(const float*)d_in[26],(const float*)d_in[27],
    (const int*)d_in[28],
    (const float*)d_in[29], ws);
  cfc_main<<<32,512,0,stream>>>(
    (const float*)d_in[0],(const float*)d_in[1],
    (const float*)d_in[15],(const float*)d_in[16],(const float*)d_in[17],(const float*)d_in[18],
    (const float*)d_in[30], ws, (float*)d_out);
}